// Round 1
// baseline (231.091 us; speedup 1.0000x reference)
//
#include <hip/hip_runtime.h>
#include <hip/hip_bf16.h>
#include <stdint.h>

#define Bn 2
#define Np 50000
#define Cc 81
#define CM1 80
#define KSEL 2048
#define NDET 100
#define NBUCK 4096
#define BUCK_BASE 0x3D000000u
#define BUCK_SHIFT 14
#define SELCAP 4096
#define IMG_W 1333.0f
#define IMG_H 800.0f
#define SCORE_TH 0.05f
#define MIN_SZ 0.01f
#define NMS_TH 0.5f
#define LBLOFF 1401.0f
#define BBOX_CLIP_F 4.135166556742356f

typedef unsigned long long u64;
typedef unsigned int u32;

__device__ __forceinline__ u64 shfl64(u64 v, int src) {
  int lo = __shfl((int)(u32)v, src, 64);
  int hi = __shfl((int)(u32)(v >> 32), src, 64);
  return ((u64)(u32)hi << 32) | (u32)lo;
}

// Torchvision BoxCoder.decode + clip, non-contracted fp32 to match numpy/XLA.
__device__ __forceinline__ void decode_box(int row, int c,
    const float* __restrict__ reg, const float* __restrict__ props,
    float& x1, float& y1, float& x2, float& y2) {
  const float* pr = props + (size_t)row * 4;
  float px1 = pr[0], py1 = pr[1], px2 = pr[2], py2 = pr[3];
  float w = __fsub_rn(px2, px1), h = __fsub_rn(py2, py1);
  float cx = __fadd_rn(px1, 0.5f * w), cy = __fadd_rn(py1, 0.5f * h);
  const float4 rel = *reinterpret_cast<const float4*>(reg + ((size_t)row * Cc + c) * 4);
  float dx = __fdiv_rn(rel.x, 10.f), dy = __fdiv_rn(rel.y, 10.f);
  float dw = fminf(__fdiv_rn(rel.z, 5.f), BBOX_CLIP_F);
  float dh = fminf(__fdiv_rn(rel.w, 5.f), BBOX_CLIP_F);
  float pcx = __fadd_rn(__fmul_rn(dx, w), cx);
  float pcy = __fadd_rn(__fmul_rn(dy, h), cy);
  float pw = __fmul_rn(expf(dw), w);
  float ph = __fmul_rn(expf(dh), h);
  x1 = fminf(fmaxf(__fsub_rn(pcx, 0.5f * pw), 0.f), IMG_W);
  y1 = fminf(fmaxf(__fsub_rn(pcy, 0.5f * ph), 0.f), IMG_H);
  x2 = fminf(fmaxf(__fadd_rn(pcx, 0.5f * pw), 0.f), IMG_W);
  y2 = fminf(fmaxf(__fadd_rn(pcy, 0.5f * ph), 0.f), IMG_H);
}

// Pass 1: one wave per proposal. Softmax over 81 classes, decode candidates
// with score>thresh, push (score_bits<<32)|~idx keys via LDS-buffered
// compaction + LDS histogram on score bit-pattern buckets.
__global__ __launch_bounds__(256) void pass1_kernel(
    const float* __restrict__ logits, const float* __restrict__ reg,
    const float* __restrict__ props, u64* __restrict__ cand,
    u32* __restrict__ gcnt, u32* __restrict__ ghist, int cap)
{
  __shared__ u64 lbuf[2048];
  __shared__ u32 lhist[NBUCK];
  __shared__ u32 lcnt;
  __shared__ u32 sbase;
  const int b = blockIdx.y;
  const int tid = threadIdx.x;
  const int wave = tid >> 6, lane = tid & 63;
  for (int hh = tid; hh < NBUCK; hh += 256) lhist[hh] = 0;
  if (tid == 0) lcnt = 0;
  __syncthreads();
  const int ITERS = (Np + 2047) / 2048;
  for (int it = 0; it < ITERS; ++it) {
    const int n = it * 2048 + blockIdx.x * 4 + wave;
    if (n < Np) {
      const int row = b * Np + n;
      const float* lrow = logits + (size_t)row * Cc;
      float l0 = lrow[lane];
      float l1 = (lane < Cc - 64) ? lrow[64 + lane] : -3.4e38f;
      float mx = fmaxf(l0, l1);
      #pragma unroll
      for (int o = 32; o; o >>= 1) mx = fmaxf(mx, __shfl_xor(mx, o, 64));
      float e0 = expf(l0 - mx);
      float e1 = (lane < Cc - 64) ? expf(l1 - mx) : 0.f;
      float s = e0 + e1;
      #pragma unroll
      for (int o = 32; o; o >>= 1) s += __shfl_xor(s, o, 64);
      const float thr = SCORE_TH * s;   // e/s > 0.05 boundary never reaches top-2048
      #pragma unroll
      for (int slot = 0; slot < 2; ++slot) {
        const int c = slot ? (64 + lane) : lane;
        const float e = slot ? e1 : e0;
        if (c >= 1 && c < Cc && e > thr) {
          float x1, y1, x2, y2;
          decode_box(row, c, reg, props, x1, y1, x2, y2);
          if (__fsub_rn(x2, x1) >= MIN_SZ && __fsub_rn(y2, y1) >= MIN_SZ) {
            const float score = __fdiv_rn(e, s);
            const u32 sb = __float_as_uint(score);
            const u32 idx = (u32)(n * CM1 + (c - 1));
            const u64 key = ((u64)sb << 32) | (u32)(~idx);
            u32 p = atomicAdd(&lcnt, 1u);
            if (p < 2048u) lbuf[p] = key;
            u32 bk = (sb - BUCK_BASE) >> BUCK_SHIFT;
            if (bk > (u32)(NBUCK - 1)) bk = NBUCK - 1;
            atomicAdd(&lhist[bk], 1u);
          }
        }
      }
    }
    __syncthreads();
    u32 cnt = lcnt;
    if (cnt > 1664u || (it == ITERS - 1 && cnt > 0u)) {
      if (cnt > 2048u) cnt = 2048u;
      if (tid == 0) sbase = atomicAdd(&gcnt[b], cnt);
      __syncthreads();
      for (u32 i = tid; i < cnt; i += 256) {
        u32 p = sbase + i;
        if (p < (u32)cap) cand[(size_t)b * cap + p] = lbuf[i];
      }
      __syncthreads();
      if (tid == 0) lcnt = 0;
    }
    __syncthreads();
  }
  for (int hh = tid; hh < NBUCK; hh += 256) {
    u32 v = lhist[hh];
    if (v) atomicAdd(&ghist[b * NBUCK + hh], v);
  }
}

// Find threshold bucket T = largest h with suffix_count(h) >= KSEL (0 if total<KSEL).
__global__ void thresh_kernel(const u32* __restrict__ ghist, u32* __restrict__ gT) {
  const int b = blockIdx.x;
  const int lane = threadIdx.x;  // 64 threads
  const u32* h = ghist + b * NBUCK;
  const int SEG = NBUCK / 64;
  u32 part = 0;
  for (int t = 0; t < SEG; ++t) part += h[lane * SEG + t];
  u32 suf = part;
  #pragma unroll
  for (int o = 1; o < 64; o <<= 1) {
    u32 v = __shfl_down(suf, o, 64);
    if (lane + o < 64) suf += v;
  }
  u64 ok = __ballot(suf >= (u32)KSEL);
  int l0 = ok ? (63 - __clzll(ok)) : -1;
  u32 sufN = __shfl(suf, (l0 >= 0 && l0 < 63) ? (l0 + 1) : 0, 64);
  if (l0 >= 63 || l0 < 0) sufN = 0;
  if (lane == 0) {
    u32 T = 0;
    if (l0 >= 0) {
      u32 acc = sufN;
      const int base = l0 * SEG;
      for (int t = SEG - 1; t >= 0; --t) {
        acc += h[base + t];
        if (acc >= (u32)KSEL) { T = (u32)(base + t); break; }
      }
    }
    gT[b] = T;
  }
}

__global__ __launch_bounds__(256) void collect_kernel(
    const u64* __restrict__ cand, const u32* __restrict__ gcnt,
    const u32* __restrict__ gT, u64* __restrict__ selbuf,
    u32* __restrict__ nsel, int cap)
{
  const int b = blockIdx.y;
  u32 cnt = gcnt[b];
  if (cnt > (u32)cap) cnt = (u32)cap;
  const u32 i = blockIdx.x * 256 + threadIdx.x;
  if (i >= cnt) return;
  const u64 key = cand[(size_t)b * cap + i];
  const u32 sb = (u32)(key >> 32);
  u32 bk = (sb - BUCK_BASE) >> BUCK_SHIFT;
  if (bk > (u32)(NBUCK - 1)) bk = NBUCK - 1;
  if (bk >= gT[b]) {
    u32 p = atomicAdd(&nsel[b], 1u);
    if (p < (u32)SELCAP) selbuf[b * SELCAP + p] = key;
  }
}

// Bitonic-sort the <=4096 boundary candidates descending (score desc, idx asc),
// decode the top-2048, store SoA: clipped box, class-offset box, area, score, label.
__global__ __launch_bounds__(1024) void sort_decode_kernel(
    const u64* __restrict__ selbuf, const u32* __restrict__ nsel,
    const float* __restrict__ reg, const float* __restrict__ props,
    float* __restrict__ sel_data)
{
  __shared__ u64 keys[SELCAP];
  const int b = blockIdx.x;
  const int tid = threadIdx.x;
  u32 n = nsel[b];
  if (n > (u32)SELCAP) n = SELCAP;
  for (int i = tid; i < SELCAP; i += 1024)
    keys[i] = (i < (int)n) ? selbuf[b * SELCAP + i] : 0ull;
  __syncthreads();
  for (u32 k = 2; k <= (u32)SELCAP; k <<= 1) {
    for (u32 j = k >> 1; j; j >>= 1) {
      for (u32 i = tid; i < (u32)SELCAP; i += 1024) {
        u32 ix = i ^ j;
        if (ix > i) {
          u64 a = keys[i], c2 = keys[ix];
          bool up = ((i & k) == 0);
          if (up ? (a < c2) : (a > c2)) { keys[i] = c2; keys[ix] = a; }
        }
      }
      __syncthreads();
    }
  }
  float* S = sel_data + (size_t)b * 12 * KSEL;
  for (int t = tid; t < KSEL; t += 1024) {
    const u64 key = keys[t];
    float x1 = 0, y1 = 0, x2 = 0, y2 = 0, score = 0, lab = 0;
    if (key) {
      const u32 sb = (u32)(key >> 32);
      const u32 idx = ~(u32)key;
      const int n_ = (int)(idx / CM1);
      const int c = (int)(idx % CM1) + 1;
      score = __uint_as_float(sb);
      decode_box(b * Np + n_, c, reg, props, x1, y1, x2, y2);
      lab = (float)c;
    }
    const float offv = __fmul_rn(lab, LBLOFF);
    const float ox1 = __fadd_rn(x1, offv), oy1 = __fadd_rn(y1, offv);
    const float ox2 = __fadd_rn(x2, offv), oy2 = __fadd_rn(y2, offv);
    const float area = __fmul_rn(__fsub_rn(ox2, ox1), __fsub_rn(oy2, oy1));
    S[0*KSEL+t]=x1;  S[1*KSEL+t]=y1;  S[2*KSEL+t]=x2;  S[3*KSEL+t]=y2;
    S[4*KSEL+t]=ox1; S[5*KSEL+t]=oy1; S[6*KSEL+t]=ox2; S[7*KSEL+t]=oy2;
    S[8*KSEL+t]=area; S[9*KSEL+t]=score; S[10*KSEL+t]=lab;
  }
}

// Suppression matrix: one wave per row i, lane j computes iou(i, t*64+j),
// __ballot IS the 64-bit mask word (conflict-free LDS access).
__global__ __launch_bounds__(256) void mask_kernel(
    const float* __restrict__ sel_data, u64* __restrict__ mask)
{
  __shared__ float sx1[KSEL], sy1[KSEL], sx2[KSEL], sy2[KSEL], sar[KSEL];
  const int b = blockIdx.y;
  const float* S = sel_data + (size_t)b * 12 * KSEL;
  for (int i = threadIdx.x; i < KSEL; i += 256) {
    sx1[i] = S[4*KSEL+i]; sy1[i] = S[5*KSEL+i];
    sx2[i] = S[6*KSEL+i]; sy2[i] = S[7*KSEL+i];
    sar[i] = S[8*KSEL+i];
  }
  __syncthreads();
  const int wave = threadIdx.x >> 6, lane = threadIdx.x & 63;
  const int i = blockIdx.x * 4 + wave;
  const float ix1 = sx1[i], iy1 = sy1[i], ix2 = sx2[i], iy2 = sy2[i], ia = sar[i];
  u64* mrow = mask + ((size_t)(b * KSEL + i)) * 32;
  for (int t = 0; t < 32; ++t) {
    const int j = (t << 6) + lane;
    const float ltx = fmaxf(ix1, sx1[j]), lty = fmaxf(iy1, sy1[j]);
    const float rbx = fminf(ix2, sx2[j]), rby = fminf(iy2, sy2[j]);
    const float wx = fmaxf(__fsub_rn(rbx, ltx), 0.f);
    const float wy = fmaxf(__fsub_rn(rby, lty), 0.f);
    const float inter = __fmul_rn(wx, wy);
    const float denom = __fadd_rn(__fsub_rn(__fadd_rn(ia, sar[j]), inter), 1e-9f);
    const float iou = __fdiv_rn(inter, denom);
    const u64 word = __ballot(iou > NMS_TH);
    if (lane == 0) mrow[t] = word;
  }
}

// Greedy NMS over sorted candidates, early-exit at 100 keeps, write outputs.
__global__ __launch_bounds__(64) void nms_out_kernel(
    const float* __restrict__ sel_data, const u64* __restrict__ mask,
    float* __restrict__ out)
{
  const int b = blockIdx.x;
  const int lane = threadIdx.x;
  const float* S = sel_data + (size_t)b * 12 * KSEL;
  __shared__ unsigned short keptIdx[NDET];
  u64 R = 0;   // lanes 0..31 hold the running removed-mask words
  int kc = 0;
  for (int c = 0; c < 32; ++c) {
    const int i = (c << 6) + lane;
    const u64 mword = mask[((size_t)(b * KSEL + i)) * 32 + c];
    const bool valid = S[9 * KSEL + i] > 0.f;
    const u64 vm = __ballot(valid);
    const u64 Rc = shfl64(R, c);
    u64 rem = Rc, keepm = 0;
    for (int j = 0; j < 64; ++j) {
      const u64 mj = shfl64(mword, j);
      if (!((rem >> j) & 1ull) && ((vm >> j) & 1ull)) {
        keepm |= 1ull << j;
        rem |= mj;
      }
    }
    if ((keepm >> lane) & 1ull) {
      const int pos = kc + __popcll(keepm & ((1ull << lane) - 1ull));
      if (pos < NDET) keptIdx[pos] = (unsigned short)i;
    }
    kc += __popcll(keepm);
    if (kc >= NDET) break;
    u64 km = keepm;
    while (km) {
      const int j = (int)__builtin_ctzll(km);
      km &= km - 1;
      if (lane < 32) R |= mask[((size_t)(b * KSEL + (c << 6) + j)) * 32 + lane];
    }
  }
  __syncthreads();
  const int kcl = (kc < NDET) ? kc : NDET;
  for (int k = lane; k < NDET; k += 64) {
    float bx1 = 0, by1 = 0, bx2 = 0, by2 = 0, sc = 0, lb = -1.f;
    if (k < kcl) {
      const int i = keptIdx[k];
      bx1 = S[0*KSEL+i]; by1 = S[1*KSEL+i]; bx2 = S[2*KSEL+i]; by2 = S[3*KSEL+i];
      sc = S[9*KSEL+i];  lb = S[10*KSEL+i];
    }
    float* ob = out + (size_t)b * NDET * 4;
    ob[k*4+0] = bx1; ob[k*4+1] = by1; ob[k*4+2] = bx2; ob[k*4+3] = by2;
    out[Bn*NDET*4 + b*NDET + k] = sc;
    out[Bn*NDET*4 + Bn*NDET + b*NDET + k] = lb;
  }
}

extern "C" void kernel_launch(void* const* d_in, const int* in_sizes, int n_in,
                              void* d_out, int out_size, void* d_ws, size_t ws_size,
                              hipStream_t stream) {
  const float* logits = (const float*)d_in[0];
  const float* reg    = (const float*)d_in[1];
  const float* props  = (const float*)d_in[2];
  float* out = (float*)d_out;
  char* ws = (char*)d_ws;

  u32* gcnt  = (u32*)ws;          // 2
  u32* nsel  = (u32*)(ws + 8);    // 2
  u32* gT    = (u32*)(ws + 16);   // 2
  u32* ghist = (u32*)(ws + 64);   // Bn*NBUCK
  size_t off = 64 + (size_t)Bn * NBUCK * 4;
  off = (off + 255) & ~(size_t)255;
  u64* selbuf = (u64*)(ws + off);   off += (size_t)Bn * SELCAP * 8;
  float* sel_data = (float*)(ws + off); off += (size_t)Bn * 12 * KSEL * 4;
  u64* mask = (u64*)(ws + off);     off += (size_t)Bn * KSEL * 32 * 8;
  size_t remain = (ws_size > off) ? (ws_size - off) : 0;
  size_t capz = remain / ((size_t)Bn * 8);
  int cap = (capz > (size_t)(1 << 19)) ? (1 << 19) : (int)capz;
  if (cap < 1) cap = 1;
  u64* cand = (u64*)(ws + off);

  hipMemsetAsync(d_ws, 0, 64 + (size_t)Bn * NBUCK * 4, stream);
  pass1_kernel<<<dim3(512, Bn), 256, 0, stream>>>(logits, reg, props, cand, gcnt, ghist, cap);
  thresh_kernel<<<dim3(Bn), 64, 0, stream>>>(ghist, gT);
  collect_kernel<<<dim3((u32)((cap + 255) / 256), Bn), 256, 0, stream>>>(cand, gcnt, gT, selbuf, nsel, cap);
  sort_decode_kernel<<<dim3(Bn), 1024, 0, stream>>>(selbuf, nsel, reg, props, sel_data);
  mask_kernel<<<dim3(KSEL / 4, Bn), 256, 0, stream>>>(sel_data, mask);
  nms_out_kernel<<<dim3(Bn), 64, 0, stream>>>(sel_data, mask, out);
}